// Round 11
// baseline (219.825 us; speedup 1.0000x reference)
//
#include <hip/hip_runtime.h>
#include <hip/hip_bf16.h>
#include <string.h>

// Problem constants (B=2, S=2048, D=1024, H=16, hd=64)
#define BB 2
#define SS 2048
#define DD 1024
#define NH 16
#define TT (BB * SS)       // 4096 rows total
#define N3 (3 * DD)        // 3072
#define A_SIZE (TT * DD)                  // 4194304 floats (output "a")
#define PRESENT_HALF (BB * NH * SS * 64)  // 4194304 floats per k/v half
#define C2Q 0.18033688011112043f          // log2(e)/8, folded into q in gemm1 epilogue

typedef __attribute__((ext_vector_type(8))) short short8;
typedef __attribute__((ext_vector_type(4))) float floatx4;
typedef __attribute__((ext_vector_type(8))) unsigned short ushort8;

__device__ __forceinline__ unsigned short f2bf(float f) {
    union { float f; unsigned u; } v; v.f = f;
    unsigned r = v.u + 0x7fffu + ((v.u >> 16) & 1u);
    return (unsigned short)(r >> 16);
}
__device__ __forceinline__ unsigned pack2bf(float a, float b) {
    __hip_bfloat162 h = __float22bfloat162_rn(float2{a, b});
    unsigned u; memcpy(&u, &h, 4); return u;
}
__device__ __forceinline__ float bf2f(unsigned short u) {
    union { unsigned u; float f; } v; v.u = ((unsigned)u) << 16; return v.f;
}

// async global->LDS, 16B per lane. lds base must be WAVE-UNIFORM; lane i lands at lds + i*16.
__device__ __forceinline__ void async16(const unsigned short* g, unsigned short* lds) {
    __builtin_amdgcn_global_load_lds(
        (const __attribute__((address_space(1))) unsigned int*)g,
        (__attribute__((address_space(3))) unsigned int*)lds,
        16, 0, 0);
}

// ---------------- fused prep: cast x (fp32->bf16) + both weight transposes ----------------
__device__ __forceinline__ void tc_body(const float* __restrict__ src,
                                        unsigned short* __restrict__ dst,
                                        int R, int C, int bx, int by, int tid,
                                        float (*tile)[33]) {
    const int c0 = bx * 32, r0 = by * 32;
    const int tx = tid & 31, ty = tid >> 5;
    for (int i = ty; i < 32; i += 8)
        tile[i][tx] = src[(size_t)(r0 + i) * C + c0 + tx];
    __syncthreads();
    for (int i = ty; i < 32; i += 8)
        dst[(size_t)(c0 + i) * R + r0 + tx] = f2bf(tile[tx][i]);
}

__global__ __launch_bounds__(256)
void prep_kernel(const float* __restrict__ x, unsigned short* __restrict__ xb,
                 const float* __restrict__ wqkv, unsigned short* __restrict__ wqkvt,
                 const float* __restrict__ wproj, unsigned short* __restrict__ wprojt) {
    __shared__ float tile[32][33];
    const int bid = blockIdx.x;
    const int tid = threadIdx.x;
    if (bid < 2048) {
        int i = (bid * 256 + tid) * 8;
        float4 a = *(const float4*)(x + i);
        float4 b = *(const float4*)(x + i + 4);
        ushort8 o;
        o[0] = f2bf(a.x); o[1] = f2bf(a.y); o[2] = f2bf(a.z); o[3] = f2bf(a.w);
        o[4] = f2bf(b.x); o[5] = f2bf(b.y); o[6] = f2bf(b.z); o[7] = f2bf(b.w);
        *(ushort8*)(xb + i) = o;
    } else if (bid < 5120) {
        const int bb = bid - 2048;                 // grid was (96, 32)
        tc_body(wqkv, wqkvt, DD, N3, bb % 96, bb / 96, tid, tile);
    } else {
        const int bb = bid - 5120;                 // grid was (32, 32)
        tc_body(wproj, wprojt, DD, DD, bb & 31, bb >> 5, tid, tile);
    }
}

// ---------------- V transpose: qkv[t][2048+h*64+d] -> vT[(bh*64+d)][s] (r0 verbatim) --------
__global__ __launch_bounds__(256)
void vtrans_kernel(const unsigned short* __restrict__ qkv,
                   unsigned short* __restrict__ vT) {
    __shared__ unsigned short tile[64][72];
    int bh = blockIdx.x, st = blockIdx.y;
    int b = bh >> 4, h = bh & 15;
    int tid = threadIdx.x;
    int r = tid >> 2, c = (tid & 3) * 16;
    const unsigned short* src = qkv + ((size_t)(b * SS + st * 64 + r)) * 3072 + 2048 + h * 64 + c;
    *(int4*)(&tile[r][c])     = *(const int4*)(src);
    *(int4*)(&tile[r][c + 8]) = *(const int4*)(src + 8);
    __syncthreads();
    int d = tid >> 2, s0 = (tid & 3) * 16;
    unsigned short tmp[16];
    for (int e = 0; e < 16; ++e) tmp[e] = tile[s0 + e][d];
    unsigned short* dst = vT + ((size_t)bh * 64 + d) * SS + st * 64 + s0;
    *(int4*)(dst)     = *(const int4*)(tmp);
    *(int4*)(dst + 8) = *(const int4*)(tmp + 8);
}

// ---------------- qkv GEMM: 128x64 tile -> 1536 blocks = 6/CU (latency-overlap lever) -------
// r9 arithmetic: at 128^2 / 3 blocks/CU, each k-iter is ~4200cy wall vs ~700cy useful (80%
// unhidden latency). Resources allow 6 blocks/CU (24KB LDS, ~56 VGPR); only the grid capped
// occupancy. 128(M)x64(N) doubles independent barrier-groups per CU; staging stays the
// proven coalesced sr=lane>>2 map (r4: the l15 map alone costs ~14us). Wave tile 64x32.
__global__ __launch_bounds__(256)
void gemm_kernel(const unsigned short* __restrict__ A,
                 const unsigned short* __restrict__ Bt,
                 const float* __restrict__ bias,
                 unsigned short* __restrict__ out_bf,
                 float* __restrict__ out_f) {
    __shared__ unsigned short As[2][128][32];   // 16 KB
    __shared__ unsigned short Bs[2][64][32];    //  8 KB
    const int tid  = threadIdx.x;
    const int t0   = blockIdx.y * 128;
    const int n0   = blockIdx.x * 64;
    const int wave = tid >> 6, lane = tid & 63;
    const int wm = wave >> 1, wn = wave & 1;    // 2x2 wave grid, wave tile 64(M) x 32(N)
    const int l15 = lane & 15, quad = lane >> 4;

    const int sr = lane >> 2;          // 0..15  (coalesced staging map — r0-proven)
    const int sc = (lane & 3) * 8;     // 0,8,16,24

    floatx4 acc[4][2];
    for (int i = 0; i < 4; ++i)
        for (int j = 0; j < 2; ++j)
            for (int e = 0; e < 4; ++e) acc[i][j][e] = 0.f;

    const unsigned short* gA = A  + (size_t)(t0 + wave * 32 + sr) * 1024 + sc;
    const unsigned short* gB = Bt + (size_t)(n0 + wave * 16 + sr) * 1024 + sc;

    async16(gA,             &As[0][wave * 32][0]);
    async16(gA + 16 * 1024, &As[0][wave * 32 + 16][0]);
    async16(gB,             &Bs[0][wave * 16][0]);

    for (int kt = 0; kt < 32; ++kt) {
        const int cur = kt & 1;
        __syncthreads();   // drains vmcnt -> buf[cur] ready; everyone done reading buf[cur^1]
        if (kt < 31) {
            const int k1 = (kt + 1) * 32;
            async16(gA + k1,             &As[cur ^ 1][wave * 32][0]);
            async16(gA + k1 + 16 * 1024, &As[cur ^ 1][wave * 32 + 16][0]);
            async16(gB + k1,             &Bs[cur ^ 1][wave * 16][0]);
        }
        short8 af[4], bfr[2];
        for (int mt = 0; mt < 4; ++mt)
            af[mt] = *(const short8*)(&As[cur][wm * 64 + mt * 16 + l15][quad * 8]);
        for (int nt = 0; nt < 2; ++nt)
            bfr[nt] = *(const short8*)(&Bs[cur][wn * 32 + nt * 16 + l15][quad * 8]);
        for (int mt = 0; mt < 4; ++mt)
            for (int nt = 0; nt < 2; ++nt)   // swapped operands: acc = C^T fragments
                acc[mt][nt] = __builtin_amdgcn_mfma_f32_16x16x32_bf16(bfr[nt], af[mt], acc[mt][nt], 0, 0, 0);
    }

    // epilogue: acc[mt][nt] col(l15)=t-local, row(quad*4+r)=n-local -> packed stores
    const float qs = (n0 < 1024) ? C2Q : 1.0f;   // 64-col block fully inside one region
    const int cb = n0 + wn * 32;                 // 32-aligned column base of this wave
    // present decode (uniform per wave; 32-col span never crosses a head boundary)
    const int half = (cb >= 2048) ? 1 : 0;
    const int ckv  = cb - 1024 - half * 1024;    // 0..1023 when cb >= 1024
    const int hh   = ckv >> 6, dbase = ckv & 63; // head, d-offset (0 or 32)
    for (int mt = 0; mt < 4; ++mt) {
        const int t = t0 + wm * 64 + mt * 16 + l15;
        unsigned short* po = out_bf + (size_t)t * 3072 + cb;
        float* pres = nullptr;
        if (cb >= 1024) {   // k/v columns: also write fp32 present (qs==1 here)
            const int b = t >> 11, s = t & 2047;
            pres = out_f + A_SIZE
                 + (((size_t)(half * 2 + b)) * 16 + hh) * (SS * 64) + (size_t)s * 64 + dbase;
        }
        for (int nt = 0; nt < 2; ++nt) {
            float4 b4 = *(const float4*)(bias + cb + nt * 16 + quad * 4);
            float v0 = (acc[mt][nt][0] + b4.x) * qs;
            float v1 = (acc[mt][nt][1] + b4.y) * qs;
            float v2 = (acc[mt][nt][2] + b4.z) * qs;
            float v3 = (acc[mt][nt][3] + b4.w) * qs;
            uint2 w = {pack2bf(v0, v1), pack2bf(v2, v3)};
            *(uint2*)(po + nt * 16 + quad * 4) = w;
            if (pres) {      // never re-read -> nontemporal, keep L2 for qkvb
                floatx4 pv = {v0, v1, v2, v3};
                __builtin_nontemporal_store(pv, (floatx4*)(pres + nt * 16 + quad * 4));
            }
        }
    }
}

// ---------------- proj GEMM: 128x64 tile, 512 blocks = 2/CU (r8, kept) ----------------------
__global__ __launch_bounds__(256)
void gemm_proj_kernel(const unsigned short* __restrict__ A,
                      const unsigned short* __restrict__ Bt,
                      const float* __restrict__ bias,
                      float* __restrict__ out_f) {
    __shared__ unsigned short As[2][128][32];   // 16 KB
    __shared__ unsigned short Bs[2][64][32];    //  8 KB
    const int tid  = threadIdx.x;
    const int t0   = blockIdx.y * 128;
    const int n0   = blockIdx.x * 64;
    const int wave = tid >> 6, lane = tid & 63;
    const int wm = wave >> 1, wn = wave & 1;    // wave tile 64(M) x 32(N)
    const int l15 = lane & 15, quad = lane >> 4;

    const int sr = lane >> 2;          // 0..15
    const int sc = (lane & 3) * 8;

    floatx4 acc[4][2];
    for (int i = 0; i < 4; ++i)
        for (int j = 0; j < 2; ++j)
            for (int e = 0; e < 4; ++e) acc[i][j][e] = 0.f;

    const unsigned short* gA = A  + (size_t)(t0 + wave * 32 + sr) * 1024 + sc;
    const unsigned short* gB = Bt + (size_t)(n0 + wave * 16 + sr) * 1024 + sc;

    async16(gA,             &As[0][wave * 32][0]);
    async16(gA + 16 * 1024, &As[0][wave * 32 + 16][0]);
    async16(gB,             &Bs[0][wave * 16][0]);

    for (int kt = 0; kt < 32; ++kt) {
        const int cur = kt & 1;
        __syncthreads();
        if (kt < 31) {
            const int k1 = (kt + 1) * 32;
            async16(gA + k1,             &As[cur ^ 1][wave * 32][0]);
            async16(gA + k1 + 16 * 1024, &As[cur ^ 1][wave * 32 + 16][0]);
            async16(gB + k1,             &Bs[cur ^ 1][wave * 16][0]);
        }
        short8 af[4], bfr[2];
        for (int mt = 0; mt < 4; ++mt)
            af[mt] = *(const short8*)(&As[cur][wm * 64 + mt * 16 + l15][quad * 8]);
        for (int nt = 0; nt < 2; ++nt)
            bfr[nt] = *(const short8*)(&Bs[cur][wn * 32 + nt * 16 + l15][quad * 8]);
        for (int mt = 0; mt < 4; ++mt)
            for (int nt = 0; nt < 2; ++nt)
                acc[mt][nt] = __builtin_amdgcn_mfma_f32_16x16x32_bf16(bfr[nt], af[mt], acc[mt][nt], 0, 0, 0);
    }

    for (int mt = 0; mt < 4; ++mt) {
        const int t = t0 + wm * 64 + mt * 16 + l15;
        float* po = out_f + (size_t)t * 1024 + n0 + wn * 32;
        for (int nt = 0; nt < 2; ++nt) {
            float4 b4 = *(const float4*)(bias + n0 + wn * 32 + nt * 16 + quad * 4);
            floatx4 v = {acc[mt][nt][0] + b4.x, acc[mt][nt][1] + b4.y,
                         acc[mt][nt][2] + b4.z, acc[mt][nt][3] + b4.w};
            __builtin_nontemporal_store(v, (floatx4*)(po + nt * 16 + quad * 4));
        }
    }
}

// ---------------- causal flash attention: QBLK=128, 8 waves, l_i via ones-MFMA (r9) ---------
__global__ __launch_bounds__(512)
void flash_kernel(const unsigned short* __restrict__ qkv,
                  const unsigned short* __restrict__ vT,
                  unsigned short* __restrict__ out) {
    __shared__ unsigned short Kt[2][64][72];     // [buf][key][d]      18 KB
    __shared__ unsigned short Vt[2][64][72];     // [buf][d][key]      18 KB
    __shared__ unsigned short Pt[8][16][72];     // per-wave P[qrow][key] bf16  18 KB

    const int bh = blockIdx.x;                   // 0..31
    const int qt = 15 - blockIdx.y;              // 0..15, longest tiles dispatch first
    const int b = bh >> 4, h = bh & 15;
    const int tid = threadIdx.x;
    const int wave = tid >> 6, lane = tid & 63;
    const int l15 = lane & 15, quad = lane >> 4;

    const size_t rowb = (size_t)b * SS;
    const int kcol = 1024 + h * 64;

    // Q as B-operand: lane n=l15 -> qrow, k=quad*8+j
    short8 bq0, bq1;
    {
        const unsigned short* qp =
            qkv + (rowb + qt * 128 + wave * 16 + l15) * 3072 + h * 64 + quad * 8;
        bq0 = *(const short8*)(qp);
        bq1 = *(const short8*)(qp + 32);
    }

    // constant all-ones A-fragment (bf16 1.0 = 0x3F80) — every output row = Sum_k P
    short8 ones8;
    #pragma unroll
    for (int e = 0; e < 8; ++e) ones8[e] = (short)0x3F80;

    floatx4 o[4];
    for (int dt = 0; dt < 4; ++dt)
        for (int e = 0; e < 4; ++e) o[dt][e] = 0.f;
    floatx4 o4;
    for (int e = 0; e < 4; ++e) o4[e] = 0.f;

    const int qrow_g = qt * 128 + wave * 16 + l15;      // global q row of this lane
    const int dtile  = (qt * 128 + wave * 16) >> 6;     // wave-uniform diagonal k-tile
    const int jmax   = 2 * qt + 1;                      // last k-tile for this block

    // staging: 512 threads, ONE int4 each for K and one for V per tile
    const int rr = tid >> 3, seg = (tid & 7) * 8;       // row 0..63, 16B segment
    const unsigned short* kb = qkv + rowb * 3072 + kcol;
    const unsigned short* vb = vT + (size_t)bh * 64 * SS;
    int4 ka, va;

    #define PREF(j) { \
        ka = *(const int4*)(kb + (size_t)((j) * 64 + rr) * 3072 + seg); \
        va = *(const int4*)(vb + (size_t)rr * SS + (j) * 64 + seg); }
    #define STAGE(bf_) { \
        *(int4*)(&Kt[bf_][rr][seg]) = ka; \
        *(int4*)(&Vt[bf_][rr][seg]) = va; }

    PREF(0);
    STAGE(0);
    PREF(1);

    for (int j = 0; j <= jmax; ++j) {
        const int cur = j & 1;
        __syncthreads();   // buf[cur] fully written; everyone done with buf[cur^1]
        if (j < jmax) {
            STAGE(cur ^ 1);
            if (j + 2 <= jmax) PREF(j + 2);
        }

        if (j <= dtile) {
            // S^T = K * Q^T : sc[nt][r] = S[qrow][key = j*64 + nt*16+quad*4+r] (log2 units)
            floatx4 sc[4];
            #pragma unroll
            for (int nt = 0; nt < 4; ++nt)
                for (int e = 0; e < 4; ++e) sc[nt][e] = 0.f;
            __builtin_amdgcn_s_setprio(1);
            #pragma unroll
            for (int nt = 0; nt < 4; ++nt) {
                const unsigned short* kp = &Kt[cur][nt * 16 + l15][quad * 8];
                short8 ak0 = *(const short8*)(kp);
                short8 ak1 = *(const short8*)(kp + 32);
                sc[nt] = __builtin_amdgcn_mfma_f32_16x16x32_bf16(ak0, bq0, sc[nt], 0, 0, 0);
                sc[nt] = __builtin_amdgcn_mfma_f32_16x16x32_bf16(ak1, bq1, sc[nt], 0, 0, 0);
            }
            __builtin_amdgcn_s_setprio(0);
            if (j == dtile) {
                #pragma unroll
                for (int nt = 0; nt < 4; ++nt)
                    for (int r = 0; r < 4; ++r)
                        if (j * 64 + nt * 16 + quad * 4 + r > qrow_g) sc[nt][r] = -1.0e30f;
            }

            // fixed-max softmax: p = exp2(s) (no VALU l-accumulation — ones-MFMA does it)
            #pragma unroll
            for (int nt = 0; nt < 4; ++nt)
                for (int r = 0; r < 4; ++r)
                    sc[nt][r] = __builtin_amdgcn_exp2f(sc[nt][r]);

            // P^T as B-operand: packed write, contiguous read-back (per-wave LDS slice)
            #pragma unroll
            for (int nt = 0; nt < 4; ++nt) {
                uint2 w = {pack2bf(sc[nt][0], sc[nt][1]), pack2bf(sc[nt][2], sc[nt][3])};
                *(uint2*)(&Pt[wave][l15][nt * 16 + quad * 4]) = w;
            }
            asm volatile("s_waitcnt lgkmcnt(0)" ::: "memory");
            short8 bp0 = *(const short8*)(&Pt[wave][l15][quad * 8]);
            short8 bp1 = *(const short8*)(&Pt[wave][l15][32 + quad * 8]);
            __builtin_amdgcn_s_setprio(1);
            #pragma unroll
            for (int dt = 0; dt < 4; ++dt) {
                const unsigned short* vp = &Vt[cur][dt * 16 + l15][quad * 8];
                short8 av0 = *(const short8*)(vp);
                short8 av1 = *(const short8*)(vp + 32);
                o[dt] = __builtin_amdgcn_mfma_f32_16x16x32_bf16(av0, bp0, o[dt], 0, 0, 0);
                o[dt] = __builtin_amdgcn_mfma_f32_16x16x32_bf16(av1, bp1, o[dt], 0, 0, 0);
            }
            o4 = __builtin_amdgcn_mfma_f32_16x16x32_bf16(ones8, bp0, o4, 0, 0, 0);
            o4 = __builtin_amdgcn_mfma_f32_16x16x32_bf16(ones8, bp1, o4, 0, 0, 0);
            __builtin_amdgcn_s_setprio(0);
        }
    }
    #undef PREF
    #undef STAGE

    // normalize: every lane's o4[0] = l_i for its qrow (all ones-rows identical)
    float inv = 1.f / o4[0];
    unsigned short* po = out + (rowb + qrow_g) * 1024 + h * 64;
    for (int dt = 0; dt < 4; ++dt) {
        uint2 w = {pack2bf(o[dt][0] * inv, o[dt][1] * inv),
                   pack2bf(o[dt][2] * inv, o[dt][3] * inv)};
        *(uint2*)(po + dt * 16 + quad * 4) = w;
    }
}

extern "C" void kernel_launch(void* const* d_in, const int* in_sizes, int n_in,
                              void* d_out, int out_size, void* d_ws, size_t ws_size,
                              hipStream_t stream) {
    const float* x        = (const float*)d_in[0];
    const float* c_attn_w = (const float*)d_in[1];
    const float* c_attn_b = (const float*)d_in[2];
    const float* c_proj_w = (const float*)d_in[3];
    const float* c_proj_b = (const float*)d_in[4];
    float* out = (float*)d_out;

    char* ws = (char*)d_ws;
    unsigned short* xb     = (unsigned short*)(ws);                      //  8 MB: [4096][1024]
    unsigned short* wqkvt  = (unsigned short*)(ws + 8388608);            //  6 MB: [3072][1024]
    unsigned short* wprojt = (unsigned short*)(ws + 14680064);           //  2 MB: [1024][1024]
    unsigned short* qkvb   = (unsigned short*)(ws + 16777216);           // 24 MB: [4096][3072]
    unsigned short* aout   = (unsigned short*)(ws + 41943040);           //  8 MB: [4096][1024]
    unsigned short* vT     = xb;  // aliases xb — dead after gemm1, vT written after

    prep_kernel<<<6144, 256, 0, stream>>>(x, xb, c_attn_w, wqkvt, c_proj_w, wprojt);
    gemm_kernel<<<dim3(N3 / 64, TT / 128), 256, 0, stream>>>(xb, wqkvt, c_attn_b, qkvb, out);
    vtrans_kernel<<<dim3(32, 32), 256, 0, stream>>>(qkvb, vT);
    flash_kernel<<<dim3(32, 16), 512, 0, stream>>>(qkvb, vT, aout);
    gemm_proj_kernel<<<dim3(DD / 64, TT / 128), 256, 0, stream>>>(aout, wprojt, c_proj_b, out);
}

// Round 12
// 197.779 us; speedup vs baseline: 1.1115x; 1.1115x over previous
//
#include <hip/hip_runtime.h>
#include <hip/hip_bf16.h>
#include <string.h>

// Problem constants (B=2, S=2048, D=1024, H=16, hd=64)
#define BB 2
#define SS 2048
#define DD 1024
#define NH 16
#define TT (BB * SS)       // 4096 rows total
#define N3 (3 * DD)        // 3072
#define A_SIZE (TT * DD)                  // 4194304 floats (output "a")
#define PRESENT_HALF (BB * NH * SS * 64)  // 4194304 floats per k/v half
#define C2Q 0.18033688011112043f          // log2(e)/8, folded into q in gemm1 epilogue

typedef __attribute__((ext_vector_type(8))) short short8;
typedef __attribute__((ext_vector_type(4))) float floatx4;
typedef __attribute__((ext_vector_type(8))) unsigned short ushort8;

__device__ __forceinline__ unsigned short f2bf(float f) {
    union { float f; unsigned u; } v; v.f = f;
    unsigned r = v.u + 0x7fffu + ((v.u >> 16) & 1u);
    return (unsigned short)(r >> 16);
}
__device__ __forceinline__ unsigned pack2bf(float a, float b) {
    __hip_bfloat162 h = __float22bfloat162_rn(float2{a, b});
    unsigned u; memcpy(&u, &h, 4); return u;
}
__device__ __forceinline__ float bf2f(unsigned short u) {
    union { unsigned u; float f; } v; v.u = ((unsigned)u) << 16; return v.f;
}

// async global->LDS, 16B per lane. lds base must be WAVE-UNIFORM; lane i lands at lds + i*16.
__device__ __forceinline__ void async16(const unsigned short* g, unsigned short* lds) {
    __builtin_amdgcn_global_load_lds(
        (const __attribute__((address_space(1))) unsigned int*)g,
        (__attribute__((address_space(3))) unsigned int*)lds,
        16, 0, 0);
}

// ---------------- fused prep: cast x (fp32->bf16) + both weight transposes ----------------
__device__ __forceinline__ void tc_body(const float* __restrict__ src,
                                        unsigned short* __restrict__ dst,
                                        int R, int C, int bx, int by, int tid,
                                        float (*tile)[33]) {
    const int c0 = bx * 32, r0 = by * 32;
    const int tx = tid & 31, ty = tid >> 5;
    for (int i = ty; i < 32; i += 8)
        tile[i][tx] = src[(size_t)(r0 + i) * C + c0 + tx];
    __syncthreads();
    for (int i = ty; i < 32; i += 8)
        dst[(size_t)(c0 + i) * R + r0 + tx] = f2bf(tile[tx][i]);
}

__global__ __launch_bounds__(256)
void prep_kernel(const float* __restrict__ x, unsigned short* __restrict__ xb,
                 const float* __restrict__ wqkv, unsigned short* __restrict__ wqkvt,
                 const float* __restrict__ wproj, unsigned short* __restrict__ wprojt) {
    __shared__ float tile[32][33];
    const int bid = blockIdx.x;
    const int tid = threadIdx.x;
    if (bid < 2048) {
        int i = (bid * 256 + tid) * 8;
        float4 a = *(const float4*)(x + i);
        float4 b = *(const float4*)(x + i + 4);
        ushort8 o;
        o[0] = f2bf(a.x); o[1] = f2bf(a.y); o[2] = f2bf(a.z); o[3] = f2bf(a.w);
        o[4] = f2bf(b.x); o[5] = f2bf(b.y); o[6] = f2bf(b.z); o[7] = f2bf(b.w);
        *(ushort8*)(xb + i) = o;
    } else if (bid < 5120) {
        const int bb = bid - 2048;                 // grid was (96, 32)
        tc_body(wqkv, wqkvt, DD, N3, bb % 96, bb / 96, tid, tile);
    } else {
        const int bb = bid - 5120;                 // grid was (32, 32)
        tc_body(wproj, wprojt, DD, DD, bb & 31, bb >> 5, tid, tile);
    }
}

// ---------------- V transpose: qkv[t][2048+h*64+d] -> vT[(bh*64+d)][s] (fallback path) ------
__global__ __launch_bounds__(256)
void vtrans_kernel(const unsigned short* __restrict__ qkv,
                   unsigned short* __restrict__ vT) {
    __shared__ unsigned short tile[64][72];
    int bh = blockIdx.x, st = blockIdx.y;
    int b = bh >> 4, h = bh & 15;
    int tid = threadIdx.x;
    int r = tid >> 2, c = (tid & 3) * 16;
    const unsigned short* src = qkv + ((size_t)(b * SS + st * 64 + r)) * 3072 + 2048 + h * 64 + c;
    *(int4*)(&tile[r][c])     = *(const int4*)(src);
    *(int4*)(&tile[r][c + 8]) = *(const int4*)(src + 8);
    __syncthreads();
    int d = tid >> 2, s0 = (tid & 3) * 16;
    unsigned short tmp[16];
    for (int e = 0; e < 16; ++e) tmp[e] = tile[s0 + e][d];
    unsigned short* dst = vT + ((size_t)bh * 64 + d) * SS + st * 64 + s0;
    *(int4*)(dst)     = *(const int4*)(tmp);
    *(int4*)(dst + 8) = *(const int4*)(tmp + 8);
}

// ---------------- qkv GEMM (r9-proven 128^2 structure) + present + optional vT fusion -------
// r11 falsified the occupancy lever for the 3rd time (6/CU = 66us > 56us): r0's 128^2 /
// 3 blocks/CU config is the empirical optimum across tile shape, buffering, vmcnt, layout,
// swizzle and occupancy (9 variants). Reverted exactly; only the epilogue grows:
// when vt_out != nullptr, v-columns (cb>=2048) also scatter-store vT[(bh*64+d)][s]
// (16-lane clusters are 32B-contiguous in s) — deletes the vtrans kernel + its 24MB pass.
__global__ __launch_bounds__(256)
void gemm_kernel(const unsigned short* __restrict__ A,
                 const unsigned short* __restrict__ Bt,
                 const float* __restrict__ bias,
                 unsigned short* __restrict__ out_bf,
                 float* __restrict__ out_f,
                 unsigned short* __restrict__ vt_out) {
    __shared__ unsigned short As[2][128][32];
    __shared__ unsigned short Bs[2][128][32];
    const int tid  = threadIdx.x;
    const int t0   = blockIdx.y * 128;
    const int n0   = blockIdx.x * 128;
    const int wave = tid >> 6, lane = tid & 63;
    const int wm = wave >> 1, wn = wave & 1;
    const int l15 = lane & 15, quad = lane >> 4;

    const int sr = lane >> 2;          // 0..15  (coalesced staging map)
    const int sc = (lane & 3) * 8;     // 0,8,16,24

    floatx4 acc[4][4];
    for (int i = 0; i < 4; ++i)
        for (int j = 0; j < 4; ++j)
            for (int e = 0; e < 4; ++e) acc[i][j][e] = 0.f;

    const unsigned short* gA = A  + (size_t)(t0 + wave * 32 + sr) * 1024 + sc;
    const unsigned short* gB = Bt + (size_t)(n0 + wave * 32 + sr) * 1024 + sc;

    async16(gA,             &As[0][wave * 32][0]);
    async16(gA + 16 * 1024, &As[0][wave * 32 + 16][0]);
    async16(gB,             &Bs[0][wave * 32][0]);
    async16(gB + 16 * 1024, &Bs[0][wave * 32 + 16][0]);

    for (int kt = 0; kt < 32; ++kt) {
        const int cur = kt & 1;
        __syncthreads();   // drains vmcnt -> buf[cur] ready; everyone done reading buf[cur^1]
        if (kt < 31) {
            const int k1 = (kt + 1) * 32;
            async16(gA + k1,             &As[cur ^ 1][wave * 32][0]);
            async16(gA + k1 + 16 * 1024, &As[cur ^ 1][wave * 32 + 16][0]);
            async16(gB + k1,             &Bs[cur ^ 1][wave * 32][0]);
            async16(gB + k1 + 16 * 1024, &Bs[cur ^ 1][wave * 32 + 16][0]);
        }
        short8 af[4], bfr[4];
        for (int mt = 0; mt < 4; ++mt)
            af[mt] = *(const short8*)(&As[cur][wm * 64 + mt * 16 + l15][quad * 8]);
        for (int nt = 0; nt < 4; ++nt)
            bfr[nt] = *(const short8*)(&Bs[cur][wn * 64 + nt * 16 + l15][quad * 8]);
        for (int mt = 0; mt < 4; ++mt)
            for (int nt = 0; nt < 4; ++nt)   // swapped operands: acc = C^T fragments
                acc[mt][nt] = __builtin_amdgcn_mfma_f32_16x16x32_bf16(bfr[nt], af[mt], acc[mt][nt], 0, 0, 0);
    }

    const float qs = (n0 < 1024) ? C2Q : 1.0f;
    const int cb = n0 + wn * 64;
    // present / vT decode (uniform per wave; 64-col span = exactly one head when cb>=1024)
    const int half = (cb >= 2048) ? 1 : 0;
    const int hh   = (cb >= 1024) ? ((cb - 1024 - half * 1024) >> 6) : 0;
    for (int mt = 0; mt < 4; ++mt) {
        const int t = t0 + wm * 64 + mt * 16 + l15;
        const int b = t >> 11, s = t & 2047;
        unsigned short* po = out_bf + (size_t)t * 3072 + cb;
        float* pres = nullptr;
        if (cb >= 1024) {   // k/v columns: also write fp32 present (qs==1 here)
            pres = out_f + A_SIZE
                 + (((size_t)(half * 2 + b)) * 16 + hh) * (SS * 64) + (size_t)s * 64;
        }
        unsigned short* pv_t = nullptr;
        if (vt_out && cb >= 2048) {  // v columns: scatter vT[(bh*64+d)][s], d = nt*16+quad*4+r
            pv_t = vt_out + ((size_t)(b * 16 + hh) * 64) * SS + s;
        }
        for (int nt = 0; nt < 4; ++nt) {
            float4 b4 = *(const float4*)(bias + cb + nt * 16 + quad * 4);
            float v0 = (acc[mt][nt][0] + b4.x) * qs;
            float v1 = (acc[mt][nt][1] + b4.y) * qs;
            float v2 = (acc[mt][nt][2] + b4.z) * qs;
            float v3 = (acc[mt][nt][3] + b4.w) * qs;
            uint2 w = {pack2bf(v0, v1), pack2bf(v2, v3)};
            *(uint2*)(po + nt * 16 + quad * 4) = w;
            if (pres) {      // never re-read -> nontemporal, keep L2 for qkvb
                floatx4 pv = {v0, v1, v2, v3};
                __builtin_nontemporal_store(pv, (floatx4*)(pres + nt * 16 + quad * 4));
            }
            if (pv_t) {      // 4 ushort scatter-stores; 16-lane clusters contiguous in s
                const int d = nt * 16 + quad * 4;
                pv_t[(size_t)(d)     * SS] = (unsigned short)(w.x & 0xffff);
                pv_t[(size_t)(d + 1) * SS] = (unsigned short)(w.x >> 16);
                pv_t[(size_t)(d + 2) * SS] = (unsigned short)(w.y & 0xffff);
                pv_t[(size_t)(d + 3) * SS] = (unsigned short)(w.y >> 16);
            }
        }
    }
}

// ---------------- proj GEMM: 128x64 tile, 512 blocks = 2/CU (r8/r9, kept) -------------------
__global__ __launch_bounds__(256)
void gemm_proj_kernel(const unsigned short* __restrict__ A,
                      const unsigned short* __restrict__ Bt,
                      const float* __restrict__ bias,
                      float* __restrict__ out_f) {
    __shared__ unsigned short As[2][128][32];   // 16 KB
    __shared__ unsigned short Bs[2][64][32];    //  8 KB
    const int tid  = threadIdx.x;
    const int t0   = blockIdx.y * 128;
    const int n0   = blockIdx.x * 64;
    const int wave = tid >> 6, lane = tid & 63;
    const int wm = wave >> 1, wn = wave & 1;    // wave tile 64(M) x 32(N)
    const int l15 = lane & 15, quad = lane >> 4;

    const int sr = lane >> 2;          // 0..15
    const int sc = (lane & 3) * 8;

    floatx4 acc[4][2];
    for (int i = 0; i < 4; ++i)
        for (int j = 0; j < 2; ++j)
            for (int e = 0; e < 4; ++e) acc[i][j][e] = 0.f;

    const unsigned short* gA = A  + (size_t)(t0 + wave * 32 + sr) * 1024 + sc;
    const unsigned short* gB = Bt + (size_t)(n0 + wave * 16 + sr) * 1024 + sc;

    async16(gA,             &As[0][wave * 32][0]);
    async16(gA + 16 * 1024, &As[0][wave * 32 + 16][0]);
    async16(gB,             &Bs[0][wave * 16][0]);

    for (int kt = 0; kt < 32; ++kt) {
        const int cur = kt & 1;
        __syncthreads();
        if (kt < 31) {
            const int k1 = (kt + 1) * 32;
            async16(gA + k1,             &As[cur ^ 1][wave * 32][0]);
            async16(gA + k1 + 16 * 1024, &As[cur ^ 1][wave * 32 + 16][0]);
            async16(gB + k1,             &Bs[cur ^ 1][wave * 16][0]);
        }
        short8 af[4], bfr[2];
        for (int mt = 0; mt < 4; ++mt)
            af[mt] = *(const short8*)(&As[cur][wm * 64 + mt * 16 + l15][quad * 8]);
        for (int nt = 0; nt < 2; ++nt)
            bfr[nt] = *(const short8*)(&Bs[cur][wn * 32 + nt * 16 + l15][quad * 8]);
        for (int mt = 0; mt < 4; ++mt)
            for (int nt = 0; nt < 2; ++nt)
                acc[mt][nt] = __builtin_amdgcn_mfma_f32_16x16x32_bf16(bfr[nt], af[mt], acc[mt][nt], 0, 0, 0);
    }

    for (int mt = 0; mt < 4; ++mt) {
        const int t = t0 + wm * 64 + mt * 16 + l15;
        float* po = out_f + (size_t)t * 1024 + n0 + wn * 32;
        for (int nt = 0; nt < 2; ++nt) {
            float4 b4 = *(const float4*)(bias + n0 + wn * 32 + nt * 16 + quad * 4);
            floatx4 v = {acc[mt][nt][0] + b4.x, acc[mt][nt][1] + b4.y,
                         acc[mt][nt][2] + b4.z, acc[mt][nt][3] + b4.w};
            __builtin_nontemporal_store(v, (floatx4*)(po + nt * 16 + quad * 4));
        }
    }
}

// ---------------- causal flash attention: QBLK=128, 8 waves, l_i via ones-MFMA (r9) ---------
__global__ __launch_bounds__(512)
void flash_kernel(const unsigned short* __restrict__ qkv,
                  const unsigned short* __restrict__ vT,
                  unsigned short* __restrict__ out) {
    __shared__ unsigned short Kt[2][64][72];     // [buf][key][d]      18 KB
    __shared__ unsigned short Vt[2][64][72];     // [buf][d][key]      18 KB
    __shared__ unsigned short Pt[8][16][72];     // per-wave P[qrow][key] bf16  18 KB

    const int bh = blockIdx.x;                   // 0..31
    const int qt = 15 - blockIdx.y;              // 0..15, longest tiles dispatch first
    const int b = bh >> 4, h = bh & 15;
    const int tid = threadIdx.x;
    const int wave = tid >> 6, lane = tid & 63;
    const int l15 = lane & 15, quad = lane >> 4;

    const size_t rowb = (size_t)b * SS;
    const int kcol = 1024 + h * 64;

    // Q as B-operand: lane n=l15 -> qrow, k=quad*8+j
    short8 bq0, bq1;
    {
        const unsigned short* qp =
            qkv + (rowb + qt * 128 + wave * 16 + l15) * 3072 + h * 64 + quad * 8;
        bq0 = *(const short8*)(qp);
        bq1 = *(const short8*)(qp + 32);
    }

    // constant all-ones A-fragment (bf16 1.0 = 0x3F80) — every output row = Sum_k P
    short8 ones8;
    #pragma unroll
    for (int e = 0; e < 8; ++e) ones8[e] = (short)0x3F80;

    floatx4 o[4];
    for (int dt = 0; dt < 4; ++dt)
        for (int e = 0; e < 4; ++e) o[dt][e] = 0.f;
    floatx4 o4;
    for (int e = 0; e < 4; ++e) o4[e] = 0.f;

    const int qrow_g = qt * 128 + wave * 16 + l15;      // global q row of this lane
    const int dtile  = (qt * 128 + wave * 16) >> 6;     // wave-uniform diagonal k-tile
    const int jmax   = 2 * qt + 1;                      // last k-tile for this block

    // staging: 512 threads, ONE int4 each for K and one for V per tile
    const int rr = tid >> 3, seg = (tid & 7) * 8;       // row 0..63, 16B segment
    const unsigned short* kb = qkv + rowb * 3072 + kcol;
    const unsigned short* vb = vT + (size_t)bh * 64 * SS;
    int4 ka, va;

    #define PREF(j) { \
        ka = *(const int4*)(kb + (size_t)((j) * 64 + rr) * 3072 + seg); \
        va = *(const int4*)(vb + (size_t)rr * SS + (j) * 64 + seg); }
    #define STAGE(bf_) { \
        *(int4*)(&Kt[bf_][rr][seg]) = ka; \
        *(int4*)(&Vt[bf_][rr][seg]) = va; }

    PREF(0);
    STAGE(0);
    PREF(1);

    for (int j = 0; j <= jmax; ++j) {
        const int cur = j & 1;
        __syncthreads();   // buf[cur] fully written; everyone done with buf[cur^1]
        if (j < jmax) {
            STAGE(cur ^ 1);
            if (j + 2 <= jmax) PREF(j + 2);
        }

        if (j <= dtile) {
            // S^T = K * Q^T : sc[nt][r] = S[qrow][key = j*64 + nt*16+quad*4+r] (log2 units)
            floatx4 sc[4];
            #pragma unroll
            for (int nt = 0; nt < 4; ++nt)
                for (int e = 0; e < 4; ++e) sc[nt][e] = 0.f;
            __builtin_amdgcn_s_setprio(1);
            #pragma unroll
            for (int nt = 0; nt < 4; ++nt) {
                const unsigned short* kp = &Kt[cur][nt * 16 + l15][quad * 8];
                short8 ak0 = *(const short8*)(kp);
                short8 ak1 = *(const short8*)(kp + 32);
                sc[nt] = __builtin_amdgcn_mfma_f32_16x16x32_bf16(ak0, bq0, sc[nt], 0, 0, 0);
                sc[nt] = __builtin_amdgcn_mfma_f32_16x16x32_bf16(ak1, bq1, sc[nt], 0, 0, 0);
            }
            __builtin_amdgcn_s_setprio(0);
            if (j == dtile) {
                #pragma unroll
                for (int nt = 0; nt < 4; ++nt)
                    for (int r = 0; r < 4; ++r)
                        if (j * 64 + nt * 16 + quad * 4 + r > qrow_g) sc[nt][r] = -1.0e30f;
            }

            // fixed-max softmax: p = exp2(s) (no VALU l-accumulation — ones-MFMA does it)
            #pragma unroll
            for (int nt = 0; nt < 4; ++nt)
                for (int r = 0; r < 4; ++r)
                    sc[nt][r] = __builtin_amdgcn_exp2f(sc[nt][r]);

            // P^T as B-operand: packed write, contiguous read-back (per-wave LDS slice)
            #pragma unroll
            for (int nt = 0; nt < 4; ++nt) {
                uint2 w = {pack2bf(sc[nt][0], sc[nt][1]), pack2bf(sc[nt][2], sc[nt][3])};
                *(uint2*)(&Pt[wave][l15][nt * 16 + quad * 4]) = w;
            }
            asm volatile("s_waitcnt lgkmcnt(0)" ::: "memory");
            short8 bp0 = *(const short8*)(&Pt[wave][l15][quad * 8]);
            short8 bp1 = *(const short8*)(&Pt[wave][l15][32 + quad * 8]);
            __builtin_amdgcn_s_setprio(1);
            #pragma unroll
            for (int dt = 0; dt < 4; ++dt) {
                const unsigned short* vp = &Vt[cur][dt * 16 + l15][quad * 8];
                short8 av0 = *(const short8*)(vp);
                short8 av1 = *(const short8*)(vp + 32);
                o[dt] = __builtin_amdgcn_mfma_f32_16x16x32_bf16(av0, bp0, o[dt], 0, 0, 0);
                o[dt] = __builtin_amdgcn_mfma_f32_16x16x32_bf16(av1, bp1, o[dt], 0, 0, 0);
            }
            o4 = __builtin_amdgcn_mfma_f32_16x16x32_bf16(ones8, bp0, o4, 0, 0, 0);
            o4 = __builtin_amdgcn_mfma_f32_16x16x32_bf16(ones8, bp1, o4, 0, 0, 0);
            __builtin_amdgcn_s_setprio(0);
        }
    }
    #undef PREF
    #undef STAGE

    // normalize: every lane's o4[0] = l_i for its qrow (all ones-rows identical)
    float inv = 1.f / o4[0];
    unsigned short* po = out + (rowb + qrow_g) * 1024 + h * 64;
    for (int dt = 0; dt < 4; ++dt) {
        uint2 w = {pack2bf(o[dt][0] * inv, o[dt][1] * inv),
                   pack2bf(o[dt][2] * inv, o[dt][3] * inv)};
        *(uint2*)(po + dt * 16 + quad * 4) = w;
    }
}

extern "C" void kernel_launch(void* const* d_in, const int* in_sizes, int n_in,
                              void* d_out, int out_size, void* d_ws, size_t ws_size,
                              hipStream_t stream) {
    const float* x        = (const float*)d_in[0];
    const float* c_attn_w = (const float*)d_in[1];
    const float* c_attn_b = (const float*)d_in[2];
    const float* c_proj_w = (const float*)d_in[3];
    const float* c_proj_b = (const float*)d_in[4];
    float* out = (float*)d_out;

    char* ws = (char*)d_ws;
    unsigned short* xb     = (unsigned short*)(ws);                      //  8 MB: [4096][1024]
    unsigned short* wqkvt  = (unsigned short*)(ws + 8388608);            //  6 MB: [3072][1024]
    unsigned short* wprojt = (unsigned short*)(ws + 14680064);           //  2 MB: [1024][1024]
    unsigned short* qkvb   = (unsigned short*)(ws + 16777216);           // 24 MB: [4096][3072]
    unsigned short* aout   = (unsigned short*)(ws + 41943040);           //  8 MB: [4096][1024]

    // vT placement: prefer dedicated region at ws+48MB (enables qkv-epilogue fusion,
    // deletes the vtrans kernel). Fallback: alias xb (dead after gemm1) + vtrans kernel.
    const bool fuse_vt = (ws_size >= (size_t)58720256);  // 48MB + 8MB vT
    unsigned short* vT = fuse_vt ? (unsigned short*)(ws + 50331648) : xb;

    prep_kernel<<<6144, 256, 0, stream>>>(x, xb, c_attn_w, wqkvt, c_proj_w, wprojt);
    gemm_kernel<<<dim3(N3 / 128, TT / 128), 256, 0, stream>>>(
        xb, wqkvt, c_attn_b, qkvb, out, fuse_vt ? vT : nullptr);
    if (!fuse_vt)
        vtrans_kernel<<<dim3(32, 32), 256, 0, stream>>>(qkvb, vT);
    flash_kernel<<<dim3(32, 16), 512, 0, stream>>>(qkvb, vT, aout);
    gemm_proj_kernel<<<dim3(DD / 64, TT / 128), 256, 0, stream>>>(aout, wprojt, c_proj_b, out);
}